// Round 3
// baseline (94.096 us; speedup 1.0000x reference)
//
#include <hip/hip_runtime.h>
#include <hip/hip_bf16.h>
#include <stdint.h>

#define DEVI __device__ __forceinline__

typedef __attribute__((ext_vector_type(8))) short short8;
typedef __attribute__((ext_vector_type(16))) float f32x16;
typedef __attribute__((ext_vector_type(4))) float f32x4;
typedef unsigned short ushortT;

union U8 { short8 s8; unsigned u[4]; };

DEVI unsigned short f2bf(float f) {
  unsigned u = __builtin_bit_cast(unsigned, f);
  u += 0x7fffu + ((u >> 16) & 1u);
  return (unsigned short)(u >> 16);
}
DEVI unsigned pk2(float lo, float hi) {
  return (unsigned)f2bf(lo) | ((unsigned)f2bf(hi) << 16);
}
DEVI unsigned cvtpk(float lo, float hi) {
  unsigned r;
  asm("v_cvt_pk_bf16_f32 %0, %1, %2" : "=v"(r) : "v"(lo), "v"(hi));
  return r;
}
DEVI float exp2a(float x) { return __builtin_amdgcn_exp2f(x); }

#define MFMA32 __builtin_amdgcn_mfma_f32_32x32x16_bf16
// p = exp(S/8 - m/8) computed as exp2((S-m)*C), C = 0.125*log2(e)
#define C_L2E 0.18033688011112042f

// ---------------- prep: st K -> Kt bf16 [bh][s][c], st V -> bf16 [bh][c][s] ----
// grid 256 = 16 bh * 16 s-chunks(64); block 256
__global__ __launch_bounds__(256) void prep_kernel(
    const float* __restrict__ st, ushortT* __restrict__ ktb,
    ushortT* __restrict__ vbuf) {
  const int bid = blockIdx.x;
  const int bh = bid >> 4, ck = bid & 15;
  const int b = bh >> 3, h = bh & 7;
  const int s0 = ck * 64;
  const float* kbase = st + ((size_t)(b * 1536 + 512 + h * 64)) * 1024;
  const float* vbase = st + ((size_t)(b * 1536 + 1024 + h * 64)) * 1024;
  const int tid = threadIdx.x;
  const int c = tid >> 2, q4 = (tid & 3) * 16;

  __shared__ float kf[64][65];
  // K chunk -> LDS (row-major)
  {
    const float* kp = kbase + (size_t)c * 1024 + s0 + q4;
    f32x4 a = *(const f32x4*)kp;
    f32x4 b4 = *(const f32x4*)(kp + 4);
    f32x4 c4 = *(const f32x4*)(kp + 8);
    f32x4 d4 = *(const f32x4*)(kp + 12);
#pragma unroll
    for (int j = 0; j < 4; ++j) {
      kf[c][q4 + j] = a[j];
      kf[c][q4 + 4 + j] = b4[j];
      kf[c][q4 + 8 + j] = c4[j];
      kf[c][q4 + 12 + j] = d4[j];
    }
  }
  // V passthrough convert (coalesced)
  {
    const float* vp = vbase + (size_t)c * 1024 + s0 + q4;
    f32x4 a = *(const f32x4*)vp;
    f32x4 b4 = *(const f32x4*)(vp + 4);
    f32x4 c4 = *(const f32x4*)(vp + 8);
    f32x4 d4 = *(const f32x4*)(vp + 12);
    U8 u0, u1;
    u0.u[0] = pk2(a[0], a[1]);  u0.u[1] = pk2(a[2], a[3]);
    u0.u[2] = pk2(b4[0], b4[1]); u0.u[3] = pk2(b4[2], b4[3]);
    u1.u[0] = pk2(c4[0], c4[1]); u1.u[1] = pk2(c4[2], c4[3]);
    u1.u[2] = pk2(d4[0], d4[1]); u1.u[3] = pk2(d4[2], d4[3]);
    ushortT* op = vbuf + ((size_t)bh * 64 + c) * 1024 + s0 + q4;
    *(short8*)op = u0.s8;
    *(short8*)(op + 8) = u1.s8;
  }
  __syncthreads();
  // transposed write: Kt row s over 64 c
  {
    const int s = tid >> 2, c0 = (tid & 3) * 16;
    float v[16];
#pragma unroll
    for (int j = 0; j < 16; ++j) v[j] = kf[c0 + j][s];
    U8 u0, u1;
#pragma unroll
    for (int i = 0; i < 4; ++i) u0.u[i] = pk2(v[2 * i], v[2 * i + 1]);
#pragma unroll
    for (int i = 0; i < 4; ++i) u1.u[i] = pk2(v[8 + 2 * i], v[8 + 2 * i + 1]);
    ushortT* op = ktb + ((size_t)bh * 1024 + s0 + s) * 64 + c0;
    *(short8*)op = u0.s8;
    *(short8*)(op + 8) = u1.s8;
  }
}

// ---------------- Path A: attn_i = softmax(img_q^T st_k) * st_v ----------------
// No LDS, no barriers: K/V fragments straight from L2-resident bf16 buffers.
// grid 512 = 16 bh * 32 t-blocks(128); block 256 (4 waves, 32 t per wave)
DEVI void load_ktile(const ushortT* kt, int s0, int ln, int hi, short8 (&kf)[8]) {
  const ushortT* kr0 = kt + (size_t)(s0 + ln) * 64 + hi * 8;
  const ushortT* kr1 = kt + (size_t)(s0 + 32 + ln) * 64 + hi * 8;
#pragma unroll
  for (int kk = 0; kk < 4; ++kk) {
    kf[kk] = *(const short8*)(kr0 + kk * 16);
    kf[4 + kk] = *(const short8*)(kr1 + kk * 16);
  }
}

DEVI void step_tile(const ushortT* kt, const ushortT* vv, int t, int ln, int hi,
                    short8 (&kc)[8], short8 (&kn)[8], const short8 (&qf)[4],
                    f32x16& o0, f32x16& o1, float& m, float& l) {
  // QK^T: D[s][t], s rows = K^T
  f32x16 sc0 = {}, sc1 = {};
  __builtin_amdgcn_s_setprio(1);
#pragma unroll
  for (int kk = 0; kk < 4; ++kk) sc0 = MFMA32(kc[kk], qf[kk], sc0, 0, 0, 0);
#pragma unroll
  for (int kk = 0; kk < 4; ++kk) sc1 = MFMA32(kc[4 + kk], qf[kk], sc1, 0, 0, 0);
  __builtin_amdgcn_s_setprio(0);

  // issue V loads (consumed after softmax ~ hides L2 latency)
  const int s0 = t * 64;
  short8 vf[8];
  {
    const ushortT* vr0 = vv + (size_t)ln * 1024 + s0 + hi * 8;
    const ushortT* vr1 = vv + (size_t)(32 + ln) * 1024 + s0 + hi * 8;
#pragma unroll
    for (int ss = 0; ss < 2; ++ss)
#pragma unroll
      for (int kk = 0; kk < 2; ++kk) {
        vf[ss * 4 + kk * 2 + 0] = *(const short8*)(vr0 + ss * 32 + kk * 16);
        vf[ss * 4 + kk * 2 + 1] = *(const short8*)(vr1 + ss * 32 + kk * 16);
      }
  }
  // prefetch next K tile
  const int tn = (t + 1 < 16) ? t + 1 : 15;
  load_ktile(kt, tn * 64, ln, hi, kn);

  // online softmax (this lane holds 32 of 64 s; partner lane the rest)
  float mx[8];
#pragma unroll
  for (int i = 0; i < 8; ++i)
    mx[i] = fmaxf(fmaxf(sc0[i], sc0[i + 8]), fmaxf(sc1[i], sc1[i + 8]));
#pragma unroll
  for (int i = 0; i < 4; ++i) mx[i] = fmaxf(mx[i], mx[i + 4]);
  float tmax = fmaxf(fmaxf(mx[0], mx[1]), fmaxf(mx[2], mx[3]));
  tmax = fmaxf(tmax, __shfl_xor(tmax, 32));

  if (!__all(tmax <= m + 16.0f)) {  // defer-max: skip rescale for small growth
    const float mnew = fmaxf(m, tmax);
    const float corr = exp2a((m - mnew) * C_L2E);
    m = mnew;
    l *= corr;
#pragma unroll
    for (int q = 0; q < 16; ++q) { o0[q] *= corr; o1[q] *= corr; }
  }
  const float mc = m * C_L2E;
  float a0 = 0.f, a1 = 0.f, a2 = 0.f, a3 = 0.f;
#pragma unroll
  for (int q = 0; q < 16; q += 4) {
    float p0 = exp2a(fmaf(sc0[q], C_L2E, -mc));
    float p1 = exp2a(fmaf(sc0[q + 1], C_L2E, -mc));
    float p2 = exp2a(fmaf(sc0[q + 2], C_L2E, -mc));
    float p3 = exp2a(fmaf(sc0[q + 3], C_L2E, -mc));
    sc0[q] = p0; sc0[q + 1] = p1; sc0[q + 2] = p2; sc0[q + 3] = p3;
    a0 += p0; a1 += p1; a2 += p2; a3 += p3;
  }
#pragma unroll
  for (int q = 0; q < 16; q += 4) {
    float p0 = exp2a(fmaf(sc1[q], C_L2E, -mc));
    float p1 = exp2a(fmaf(sc1[q + 1], C_L2E, -mc));
    float p2 = exp2a(fmaf(sc1[q + 2], C_L2E, -mc));
    float p3 = exp2a(fmaf(sc1[q + 3], C_L2E, -mc));
    sc1[q] = p0; sc1[q + 1] = p1; sc1[q + 2] = p2; sc1[q + 3] = p3;
    a0 += p0; a1 += p1; a2 += p2; a3 += p3;
  }
  float ps = (a0 + a1) + (a2 + a3);
  ps += __shfl_xor(ps, 32);
  l += ps;

  // PV: redistribute P (D-layout, 4-s groups) to B-layout (8-s groups)
#pragma unroll
  for (int ss = 0; ss < 2; ++ss) {
    const f32x16& sc = ss ? sc1 : sc0;
    unsigned pb[8], oth[8];
#pragma unroll
    for (int i = 0; i < 8; ++i) pb[i] = cvtpk(sc[2 * i], sc[2 * i + 1]);
#pragma unroll
    for (int i = 0; i < 8; ++i) oth[i] = __shfl_xor(pb[i], 32);
    U8 f0, f1;
    if (hi) {
      f0.u[0] = oth[2]; f0.u[1] = oth[3]; f0.u[2] = pb[2];  f0.u[3] = pb[3];
      f1.u[0] = oth[6]; f1.u[1] = oth[7]; f1.u[2] = pb[6];  f1.u[3] = pb[7];
    } else {
      f0.u[0] = pb[0];  f0.u[1] = pb[1];  f0.u[2] = oth[0]; f0.u[3] = oth[1];
      f1.u[0] = pb[4];  f1.u[1] = pb[5];  f1.u[2] = oth[4]; f1.u[3] = oth[5];
    }
    __builtin_amdgcn_s_setprio(1);
#pragma unroll
    for (int kk = 0; kk < 2; ++kk) {
      const short8 bfrag = kk ? f1.s8 : f0.s8;
      o0 = MFMA32(vf[ss * 4 + kk * 2 + 0], bfrag, o0, 0, 0, 0);
      o1 = MFMA32(vf[ss * 4 + kk * 2 + 1], bfrag, o1, 0, 0, 0);
    }
    __builtin_amdgcn_s_setprio(0);
  }
}

__global__ __launch_bounds__(256, 2) void attn_img_kernel(
    const float* __restrict__ img, const ushortT* __restrict__ ktb,
    const ushortT* __restrict__ vbuf, float* __restrict__ out0) {
  const int tid = threadIdx.x;
  const int bid = blockIdx.x;
  const int bh = bid >> 5, tb = bid & 31;
  const int b = bh >> 3, h = bh & 7;
  const float* qbase = img + ((size_t)(b * 1536 + h * 64)) * 4096;
  const ushortT* kt = ktb + (size_t)bh * 1024 * 64;
  const ushortT* vv = vbuf + (size_t)bh * 64 * 1024;
  float* obase = out0 + ((size_t)(b * 512 + h * 64)) * 4096;

  const int w = tid >> 6, lane = tid & 63, hi = lane >> 5, ln = lane & 31;
  const int tcol = tb * 128 + w * 32 + ln;

  // Q fragments (B-operand): element j of qf[k] = Q[k*16 + hi*8 + j][tcol]
  short8 qf[4];
#pragma unroll
  for (int k = 0; k < 4; ++k) {
    const float* qp = qbase + (size_t)(k * 16 + hi * 8) * 4096 + tcol;
    float q8[8];
#pragma unroll
    for (int j = 0; j < 8; ++j) q8[j] = qp[(size_t)j * 4096];
    U8 u;
#pragma unroll
    for (int i = 0; i < 4; ++i) u.u[i] = pk2(q8[2 * i], q8[2 * i + 1]);
    qf[k] = u.s8;
  }

  f32x16 oacc0 = {}, oacc1 = {};
  float m = -3.0e38f, l = 0.0f;

  short8 kA[8], kB[8];
  load_ktile(kt, 0, ln, hi, kA);
#pragma unroll
  for (int i = 0; i < 8; ++i) {
    step_tile(kt, vv, 2 * i, ln, hi, kA, kB, qf, oacc0, oacc1, m, l);
    step_tile(kt, vv, 2 * i + 1, ln, hi, kB, kA, qf, oacc0, oacc1, m, l);
  }

  const float inv = 1.0f / l;
#pragma unroll
  for (int q = 0; q < 16; ++q) {
    const int c = (q & 3) + 8 * (q >> 2) + 4 * hi;
    obase[(size_t)c * 4096 + tcol] = oacc0[q] * inv;
    obase[(size_t)(c + 32) * 4096 + tcol] = oacc1[q] * inv;
  }
}

// ---- Path B: attn_st = scale^2 * (V_img K_img^T) Q_st  (no softmax -> collapse) ----
template <bool PART>
__global__ __launch_bounds__(256) void gram_kernel(
    const float* __restrict__ img, float* __restrict__ Mws) {
  const int tid = threadIdx.x;
  const int bid = blockIdx.x;
  const int bh = bid >> 4;
  const int chunk = bid & 15;
  const int b = bh >> 3, h = bh & 7;
  const float* kbase = img + ((size_t)(b * 1536 + 512 + h * 64)) * 4096;
  const float* vbase = img + ((size_t)(b * 1536 + 1024 + h * 64)) * 4096;

  const int w = tid >> 6, lane = tid & 63, hi = lane >> 5, ln = lane & 31;

  f32x16 m00 = {}, m01 = {}, m10 = {}, m11 = {};
  const int sbeg = chunk * 256 + w * 64;
  for (int s0 = sbeg; s0 < sbeg + 64; s0 += 16) {
    const int sa = s0 + hi * 8;
    short8 av[2], bk[2];
#pragma unroll
    for (int ci = 0; ci < 2; ++ci) {
      const float* vp = vbase + (size_t)(ci * 32 + ln) * 4096 + sa;
      f32x4 lo = *(const f32x4*)vp, hp = *(const f32x4*)(vp + 4);
      U8 u;
      u.u[0] = pk2(lo[0], lo[1]); u.u[1] = pk2(lo[2], lo[3]);
      u.u[2] = pk2(hp[0], hp[1]); u.u[3] = pk2(hp[2], hp[3]);
      av[ci] = u.s8;
    }
#pragma unroll
    for (int cj = 0; cj < 2; ++cj) {
      const float* kp = kbase + (size_t)(cj * 32 + ln) * 4096 + sa;
      f32x4 lo = *(const f32x4*)kp, hp = *(const f32x4*)(kp + 4);
      U8 u;
      u.u[0] = pk2(lo[0], lo[1]); u.u[1] = pk2(lo[2], lo[3]);
      u.u[2] = pk2(hp[0], hp[1]); u.u[3] = pk2(hp[2], hp[3]);
      bk[cj] = u.s8;
    }
    m00 = MFMA32(av[0], bk[0], m00, 0, 0, 0);
    m01 = MFMA32(av[0], bk[1], m01, 0, 0, 0);
    m10 = MFMA32(av[1], bk[0], m10, 0, 0, 0);
    m11 = MFMA32(av[1], bk[1], m11, 0, 0, 0);
  }

  __shared__ float part[4][64][64];
#pragma unroll
  for (int q = 0; q < 16; ++q) {
    const int cr = (q & 3) + 8 * (q >> 2) + 4 * hi;
    part[w][cr][ln] = m00[q];
    part[w][cr][32 + ln] = m01[q];
    part[w][32 + cr][ln] = m10[q];
    part[w][32 + cr][32 + ln] = m11[q];
  }
  __syncthreads();

#pragma unroll
  for (int i = 0; i < 16; ++i) {
    const int e = tid + i * 256;
    const int c = e >> 6, cp = e & 63;
    const float s =
        (part[0][c][cp] + part[1][c][cp] + part[2][c][cp] + part[3][c][cp]) * 0.125f;
    if (PART)
      Mws[(size_t)bid * 4096 + c * 64 + cp] = s;
    else
      atomicAdd(&Mws[(size_t)bh * 4096 + c * 64 + cp], s);
  }
}

template <bool PART>
__global__ __launch_bounds__(256) void attn_st2_kernel(
    const float* __restrict__ st, const float* __restrict__ Mws,
    float* __restrict__ out1) {
  const int tid = threadIdx.x;
  const int bh = blockIdx.x >> 2;
  const int tt = blockIdx.x & 3;
  const int b = bh >> 3, h = bh & 7;
  const float* qbase = st + ((size_t)(b * 1536 + h * 64)) * 1024;
  float* o1 = out1 + ((size_t)(b * 512 + h * 64)) * 1024;

  __shared__ float Ms[64][64];
  char* msb = (char*)&Ms[0][0];

#pragma unroll
  for (int i = 0; i < 16; ++i) {
    const int e = tid + i * 256;
    const int c = e >> 6, cp = e & 63;
    float s;
    if (PART) {
      const float* mp = Mws + (size_t)bh * 16 * 4096 + c * 64 + cp;
      s = 0.f;
#pragma unroll
      for (int ch = 0; ch < 16; ++ch) s += mp[(size_t)ch * 4096];
    } else {
      s = Mws[(size_t)bh * 4096 + c * 64 + cp];
    }
    *(float*)(msb + c * 256 + ((cp * 4) ^ ((c & 7) << 5))) = s;
  }
  __syncthreads();

  const int w = tid >> 6, lane = tid & 63, hi = lane >> 5, ln = lane & 31;

  short8 aM0[4], aM1[4];
#pragma unroll
  for (int k = 0; k < 4; ++k) {
#pragma unroll
    for (int ci = 0; ci < 2; ++ci) {
      const int row = ci * 32 + ln;
      const int bo = k * 64 + hi * 32;
      const char* rp = msb + row * 256;
      const int swz = (row & 7) << 5;
      f32x4 lo = *(const f32x4*)(rp + (bo ^ swz));
      f32x4 hp = *(const f32x4*)(rp + ((bo + 16) ^ swz));
      U8 u;
      u.u[0] = pk2(lo[0], lo[1]); u.u[1] = pk2(lo[2], lo[3]);
      u.u[2] = pk2(hp[0], hp[1]); u.u[3] = pk2(hp[2], hp[3]);
      if (ci) aM1[k] = u.s8; else aM0[k] = u.s8;
    }
  }

#pragma unroll
  for (int nt = 0; nt < 2; ++nt) {
    const int t = tt * 256 + w * 64 + nt * 32 + ln;
    short8 bq[4];
#pragma unroll
    for (int k = 0; k < 4; ++k) {
      const float* qp = qbase + (size_t)(k * 16 + hi * 8) * 1024 + t;
      float q8[8];
#pragma unroll
      for (int j = 0; j < 8; ++j) q8[j] = qp[(size_t)j * 1024];
      U8 u;
#pragma unroll
      for (int i = 0; i < 4; ++i) u.u[i] = pk2(q8[2 * i], q8[2 * i + 1]);
      bq[k] = u.s8;
    }
    f32x16 a0 = {}, a1 = {};
#pragma unroll
    for (int k = 0; k < 4; ++k) {
      a0 = MFMA32(aM0[k], bq[k], a0, 0, 0, 0);
      a1 = MFMA32(aM1[k], bq[k], a1, 0, 0, 0);
    }
#pragma unroll
    for (int q = 0; q < 16; ++q) {
      const int cr = (q & 3) + 8 * (q >> 2) + 4 * hi;
      o1[(size_t)cr * 1024 + t] = a0[q];
      o1[(size_t)(cr + 32) * 1024 + t] = a1[q];
    }
  }
}

extern "C" void kernel_launch(void* const* d_in, const int* in_sizes, int n_in,
                              void* d_out, int out_size, void* d_ws, size_t ws_size,
                              hipStream_t stream) {
  const float* img = (const float*)d_in[0];
  const float* st = (const float*)d_in[1];
  float* out0 = (float*)d_out;
  float* out1 = out0 + (size_t)2 * 512 * 4096;
  char* ws = (char*)d_ws;
  const size_t MB = 1u << 20;

  ushortT* ktb;
  ushortT* vbuf;
  float* Ms;
  bool part = false;
  if (ws_size >= 8 * MB) {
    ktb = (ushortT*)ws; vbuf = (ushortT*)(ws + 2 * MB);
    Ms = (float*)(ws + 4 * MB); part = true;
  } else if (ws_size >= 4 * MB + 256 * 1024) {
    ktb = (ushortT*)ws; vbuf = (ushortT*)(ws + 2 * MB);
    Ms = (float*)(ws + 4 * MB);
  } else {
    // stash bf16 K/V scratch in out1's region; st2 overwrites it last (stream order)
    ktb = (ushortT*)out1; vbuf = (ushortT*)((char*)out1 + 2 * MB);
    Ms = (float*)ws;
  }

  hipLaunchKernelGGL(prep_kernel, dim3(256), dim3(256), 0, stream, st, ktb, vbuf);
  hipLaunchKernelGGL(attn_img_kernel, dim3(512), dim3(256), 0, stream, img, ktb, vbuf, out0);
  if (part) {
    hipLaunchKernelGGL((gram_kernel<true>), dim3(256), dim3(256), 0, stream, img, Ms);
    hipLaunchKernelGGL((attn_st2_kernel<true>), dim3(64), dim3(256), 0, stream, st, Ms, out1);
  } else {
    hipMemsetAsync(Ms, 0, (size_t)16 * 4096 * 4, stream);
    hipLaunchKernelGGL((gram_kernel<false>), dim3(256), dim3(256), 0, stream, img, Ms);
    hipLaunchKernelGGL((attn_st2_kernel<false>), dim3(64), dim3(256), 0, stream, st, Ms, out1);
  }
}